// Round 1
// baseline (1771.177 us; speedup 1.0000x reference)
//
#include <hip/hip_runtime.h>
#include <math.h>

#define NN 50000
#define NE 600000
#define DD 128
#define NL 4
#define NG 512
#define NT 10
#define EPSF 1e-5f

// ---------------- CSR build ----------------
__global__ void k_count(const int* __restrict__ dst, int* __restrict__ deg, int E) {
    int e = blockIdx.x * blockDim.x + threadIdx.x;
    if (e < E) atomicAdd(&deg[dst[e]], 1);
}

__global__ void k_scan(const int* __restrict__ deg, int* __restrict__ row_ptr,
                       int* __restrict__ cursor, int n) {
    __shared__ int part[1024];
    int tid = threadIdx.x;
    int chunk = (n + 1023) / 1024;
    int start = tid * chunk;
    int end = min(start + chunk, n);
    int s = 0;
    for (int i = start; i < end; i++) s += deg[i];
    part[tid] = s;
    __syncthreads();
    for (int off = 1; off < 1024; off <<= 1) {
        int v = 0;
        if (tid >= off) v = part[tid - off];
        __syncthreads();
        part[tid] += v;
        __syncthreads();
    }
    int offset = (tid == 0) ? 0 : part[tid - 1];
    for (int i = start; i < end; i++) {
        row_ptr[i] = offset;
        cursor[i] = offset;
        offset += deg[i];
    }
    if (tid == 1023) row_ptr[n] = part[1023];
}

__global__ void k_fill(const int* __restrict__ src, const int* __restrict__ dst,
                       int* __restrict__ cursor, int* __restrict__ csr_src, int E) {
    int e = blockIdx.x * blockDim.x + threadIdx.x;
    if (e < E) {
        int d = dst[e];
        int pos = atomicAdd(&cursor[d], 1);
        csr_src[pos] = src[e];
    }
}

// ---------------- degree scalars ----------------
__global__ void k_delta(const int* __restrict__ deg, float* __restrict__ dsum, int n) {
    int i = blockIdx.x * blockDim.x + threadIdx.x;
    float v = (i < n) ? log1pf((float)deg[i]) : 0.f;
    #pragma unroll
    for (int off = 32; off > 0; off >>= 1) v += __shfl_down(v, off);
    if ((threadIdx.x & 63) == 0) atomicAdd(dsum, v);
}

__global__ void k_scalars(const int* __restrict__ deg, const float* __restrict__ dsum,
                          float* __restrict__ inv_d, float* __restrict__ amp,
                          float* __restrict__ att, int n) {
    int i = blockIdx.x * blockDim.x + threadIdx.x;
    if (i >= n) return;
    float delta = *dsum / (float)n;
    float d = fmaxf((float)deg[i], 1.f);
    float ld = log1pf(d);
    inv_d[i] = 1.f / d;
    amp[i] = ld / delta;
    att[i] = delta / ld;
}

// ---------------- node embedding ----------------
__global__ void k_emb(const float* __restrict__ x, const float* __restrict__ W,
                      const float* __restrict__ b, float* __restrict__ h, int n) {
    int idx = blockIdx.x * blockDim.x + threadIdx.x;
    if (idx >= n * DD) return;
    int node = idx >> 7, c = idx & 127;
    float x0 = x[node * 3 + 0], x1 = x[node * 3 + 1], x2 = x[node * 3 + 2];
    h[idx] = x0 * W[c] + x1 * W[DD + c] + x2 * W[2 * DD + c] + b[c];
}

// ---------------- PNA aggregation ----------------
// one block (128 threads) per node; thread t owns channel t
__global__ void k_agg(const float* __restrict__ h, const int* __restrict__ row_ptr,
                      const int* __restrict__ csr_src, const float* __restrict__ inv_d,
                      float* __restrict__ aggs) {
    int node = blockIdx.x;
    int c = threadIdx.x;
    int beg = row_ptr[node], end = row_ptr[node + 1];
    float s1 = 0.f, s2 = 0.f;
    float mn = INFINITY, mx = -INFINITY;
    for (int e = beg; e < end; e++) {
        int s = csr_src[e];
        float v = h[(size_t)s * DD + c];
        s1 += v;
        s2 += v * v;
        mn = fminf(mn, v);
        mx = fmaxf(mx, v);
    }
    float id = inv_d[node];
    float mean = s1 * id;
    float var = fmaxf(s2 * id - mean * mean, 0.f);
    float sd = sqrtf(var + EPSF);
    if (beg == end) { mn = 0.f; mx = 0.f; }   // has_edge mask
    size_t base = (size_t)node * 512;
    aggs[base + c] = mean;
    aggs[base + 128 + c] = mn;
    aggs[base + 256 + c] = mx;
    aggs[base + 384 + c] = sd;
}

// ---------------- GEMM: out = A@W0 + amp*(A@W1) + att*(A@W2) + bias ----------------
// A [N,512], B (conv_W layer) [1536,128]. Tile 64 rows x 64 cols, 3 accumulators.
// BN partial sums fused into epilogue.
__global__ __launch_bounds__(256) void k_gemm(
    const float* __restrict__ A, const float* __restrict__ B,
    const float* __restrict__ bias, const float* __restrict__ amp,
    const float* __restrict__ att, float* __restrict__ outp,
    float* __restrict__ bn_sum, float* __restrict__ bn_sq, int n) {
    __shared__ float As[16 * 68];        // As[kk*68 + row]
    __shared__ float Bs[3][16][64];      // [j][kk][col]
    int tid = threadIdx.x;
    int ty = tid >> 4, tx = tid & 15;
    int row0 = blockIdx.x * 64;
    int c0 = blockIdx.y * 64;
    float acc[3][4][4];
    #pragma unroll
    for (int j = 0; j < 3; j++)
        #pragma unroll
        for (int i = 0; i < 4; i++)
            #pragma unroll
            for (int jj = 0; jj < 4; jj++) acc[j][i][jj] = 0.f;

    int a_row = tid >> 2, a_q = tid & 3;
    int b_kk = tid >> 4, b_cq = tid & 15;
    for (int k0 = 0; k0 < 512; k0 += 16) {
        int grow = row0 + a_row;
        float4 av = make_float4(0.f, 0.f, 0.f, 0.f);
        if (grow < n) av = *(const float4*)(A + (size_t)grow * 512 + k0 + a_q * 4);
        As[(a_q * 4 + 0) * 68 + a_row] = av.x;
        As[(a_q * 4 + 1) * 68 + a_row] = av.y;
        As[(a_q * 4 + 2) * 68 + a_row] = av.z;
        As[(a_q * 4 + 3) * 68 + a_row] = av.w;
        #pragma unroll
        for (int j = 0; j < 3; j++) {
            float4 bv = *(const float4*)(B + ((size_t)(j * 512 + k0 + b_kk)) * 128 + c0 + b_cq * 4);
            *(float4*)&Bs[j][b_kk][b_cq * 4] = bv;
        }
        __syncthreads();
        #pragma unroll
        for (int kk = 0; kk < 16; kk++) {
            float4 a = *(const float4*)&As[kk * 68 + ty * 4];
            float4 b0 = *(const float4*)&Bs[0][kk][tx * 4];
            float4 b1 = *(const float4*)&Bs[1][kk][tx * 4];
            float4 b2 = *(const float4*)&Bs[2][kk][tx * 4];
            float ar[4] = {a.x, a.y, a.z, a.w};
            float br0[4] = {b0.x, b0.y, b0.z, b0.w};
            float br1[4] = {b1.x, b1.y, b1.z, b1.w};
            float br2[4] = {b2.x, b2.y, b2.z, b2.w};
            #pragma unroll
            for (int i = 0; i < 4; i++) {
                #pragma unroll
                for (int jj = 0; jj < 4; jj++) {
                    acc[0][i][jj] += ar[i] * br0[jj];
                    acc[1][i][jj] += ar[i] * br1[jj];
                    acc[2][i][jj] += ar[i] * br2[jj];
                }
            }
        }
        __syncthreads();
    }
    // epilogue: combine, bias, write, BN partials
    float ps[4] = {0.f, 0.f, 0.f, 0.f}, pq[4] = {0.f, 0.f, 0.f, 0.f};
    #pragma unroll
    for (int i = 0; i < 4; i++) {
        int grow = row0 + ty * 4 + i;
        if (grow >= n) continue;
        float am = amp[grow], at = att[grow];
        #pragma unroll
        for (int jj = 0; jj < 4; jj++) {
            int col = c0 + tx * 4 + jj;
            float v = acc[0][i][jj] + am * acc[1][i][jj] + at * acc[2][i][jj] + bias[col];
            outp[(size_t)grow * DD + col] = v;
            ps[jj] += v;
            pq[jj] += v * v;
        }
    }
    float* red = As;  // reuse (1088 >= 1024)
    __syncthreads();
    #pragma unroll
    for (int jj = 0; jj < 4; jj++) red[ty * 64 + tx * 4 + jj] = ps[jj];
    __syncthreads();
    if (tid < 64) {
        float s = 0.f;
        #pragma unroll
        for (int r = 0; r < 16; r++) s += red[r * 64 + tid];
        atomicAdd(&bn_sum[c0 + tid], s);
    }
    __syncthreads();
    #pragma unroll
    for (int jj = 0; jj < 4; jj++) red[ty * 64 + tx * 4 + jj] = pq[jj];
    __syncthreads();
    if (tid < 64) {
        float s = 0.f;
        #pragma unroll
        for (int r = 0; r < 16; r++) s += red[r * 64 + tid];
        atomicAdd(&bn_sq[c0 + tid], s);
    }
}

// ---------------- BN stats -> scale/shift ----------------
__global__ void k_bnstats(const float* __restrict__ bn_sum, const float* __restrict__ bn_sq,
                          const float* __restrict__ gamma, const float* __restrict__ beta,
                          float* __restrict__ scale, float* __restrict__ shift, int n) {
    int c = threadIdx.x;
    float mu = bn_sum[c] / (float)n;
    float var = bn_sq[c] / (float)n - mu * mu;
    float sc = rsqrtf(var + EPSF) * gamma[c];
    scale[c] = sc;
    shift[c] = beta[c] - mu * sc;
}

// ---------------- BN apply + relu + residual ----------------
__global__ void k_bnapply(const float* __restrict__ outp, const float* __restrict__ scale,
                          const float* __restrict__ shift, float* __restrict__ h, int total) {
    int idx = blockIdx.x * blockDim.x + threadIdx.x;
    if (idx >= total) return;
    int c = idx & 127;
    float v = fmaxf(outp[idx] * scale[c] + shift[c], 0.f);
    h[idx] = v + h[idx];
}

// ---------------- pool + MLP ----------------
__global__ void k_pool_mlp(const float* __restrict__ h, const int* __restrict__ batch,
                           const float* __restrict__ W1, const float* __restrict__ b1,
                           const float* __restrict__ W2, const float* __restrict__ b2,
                           const float* __restrict__ W3, const float* __restrict__ b3,
                           float* __restrict__ out, int n) {
    __shared__ float gvec[128];
    __shared__ float h1[64];
    __shared__ float h2[32];
    __shared__ int srange[2];
    int g = blockIdx.x;
    int t = threadIdx.x;
    if (t < 2) {
        int target = g + t;
        int lo = 0, hi = n;
        while (lo < hi) {
            int mid = (lo + hi) >> 1;
            if (batch[mid] < target) lo = mid + 1; else hi = mid;
        }
        srange[t] = lo;
    }
    __syncthreads();
    int s = srange[0], e = srange[1];
    float acc = 0.f;
    for (int i = s; i < e; i++) acc += h[(size_t)i * DD + t];
    float cnt = fmaxf((float)(e - s), 1.f);
    gvec[t] = acc / cnt;
    __syncthreads();
    if (t < 64) {
        float a = b1[t];
        for (int k = 0; k < 128; k++) a += gvec[k] * W1[k * 64 + t];
        h1[t] = fmaxf(a, 0.f);
    }
    __syncthreads();
    if (t < 32) {
        float a = b2[t];
        for (int k = 0; k < 64; k++) a += h1[k] * W2[k * 32 + t];
        h2[t] = fmaxf(a, 0.f);
    }
    __syncthreads();
    if (t < 10) {
        float a = b3[t];
        for (int k = 0; k < 32; k++) a += h2[k] * W3[k * 10 + t];
        out[g * NT + t] = a;
    }
}

extern "C" void kernel_launch(void* const* d_in, const int* in_sizes, int n_in,
                              void* d_out, int out_size, void* d_ws, size_t ws_size,
                              hipStream_t stream) {
    const float* x      = (const float*)d_in[0];
    const int*   eidx   = (const int*)d_in[1];     // [2,E]: src then dst
    const int*   batch  = (const int*)d_in[2];
    const float* emb_W  = (const float*)d_in[3];
    const float* emb_b  = (const float*)d_in[4];
    const float* conv_W = (const float*)d_in[5];   // [L,1536,128]
    const float* conv_b = (const float*)d_in[6];   // [L,128]
    const float* bn_g   = (const float*)d_in[7];
    const float* bn_b   = (const float*)d_in[8];
    const float* W1 = (const float*)d_in[9];
    const float* b1 = (const float*)d_in[10];
    const float* W2 = (const float*)d_in[11];
    const float* b2 = (const float*)d_in[12];
    const float* W3 = (const float*)d_in[13];
    const float* b3 = (const float*)d_in[14];
    float* out = (float*)d_out;

    const int* src = eidx;
    const int* dst = eidx + NE;

    char* p = (char*)d_ws;
    auto carve = [&](size_t bytes) {
        void* r = (void*)p;
        p += (bytes + 255) & ~(size_t)255;
        return r;
    };
    int* deg      = (int*)carve(NN * 4);
    int* row_ptr  = (int*)carve((NN + 1) * 4);
    int* cursor   = (int*)carve(NN * 4);
    int* csr_src  = (int*)carve(NE * 4);
    float* inv_d  = (float*)carve(NN * 4);
    float* amp    = (float*)carve(NN * 4);
    float* att    = (float*)carve(NN * 4);
    float* dsum   = (float*)carve(4);
    float* bn_sum = (float*)carve(DD * 4);
    float* bn_sq  = (float*)carve(DD * 4);
    float* scale  = (float*)carve(DD * 4);
    float* shift  = (float*)carve(DD * 4);
    float* h      = (float*)carve((size_t)NN * DD * 4);
    float* aggs   = (float*)carve((size_t)NN * 512 * 4);
    float* outp   = (float*)carve((size_t)NN * DD * 4);

    hipMemsetAsync(deg, 0, NN * 4, stream);
    hipMemsetAsync(dsum, 0, 4, stream);

    k_count<<<(NE + 255) / 256, 256, 0, stream>>>(dst, deg, NE);
    k_scan<<<1, 1024, 0, stream>>>(deg, row_ptr, cursor, NN);
    k_fill<<<(NE + 255) / 256, 256, 0, stream>>>(src, dst, cursor, csr_src, NE);
    k_delta<<<(NN + 255) / 256, 256, 0, stream>>>(deg, dsum, NN);
    k_scalars<<<(NN + 255) / 256, 256, 0, stream>>>(deg, dsum, inv_d, amp, att, NN);
    k_emb<<<(NN * DD + 255) / 256, 256, 0, stream>>>(x, emb_W, emb_b, h, NN);

    for (int l = 0; l < NL; l++) {
        k_agg<<<NN, 128, 0, stream>>>(h, row_ptr, csr_src, inv_d, aggs);
        hipMemsetAsync(bn_sum, 0, DD * 4, stream);
        hipMemsetAsync(bn_sq, 0, DD * 4, stream);
        dim3 grid((NN + 63) / 64, 2);
        k_gemm<<<grid, 256, 0, stream>>>(aggs, conv_W + (size_t)l * 1536 * 128,
                                         conv_b + l * DD, amp, att, outp,
                                         bn_sum, bn_sq, NN);
        k_bnstats<<<1, DD, 0, stream>>>(bn_sum, bn_sq, bn_g + l * DD, bn_b + l * DD,
                                        scale, shift, NN);
        k_bnapply<<<(NN * DD + 255) / 256, 256, 0, stream>>>(outp, scale, shift, h, NN * DD);
    }

    k_pool_mlp<<<NG, 128, 0, stream>>>(h, batch, W1, b1, W2, b2, W3, b3, out, NN);
}

// Round 2
// 825.898 us; speedup vs baseline: 2.1445x; 2.1445x over previous
//
#include <hip/hip_runtime.h>
#include <math.h>

#define NN 50000
#define NE 600000
#define DD 128
#define NL 4
#define NG 512
#define NT 10
#define EPSF 1e-5f

typedef __bf16 bf16x8 __attribute__((ext_vector_type(8)));
typedef float f32x4 __attribute__((ext_vector_type(4)));

__device__ __forceinline__ unsigned short f2bf(float x) {
    union { float f; unsigned u; } v; v.f = x;
    unsigned r = v.u + 0x7FFFu + ((v.u >> 16) & 1u);
    return (unsigned short)(r >> 16);
}
__device__ __forceinline__ unsigned pack_bf2(float a, float b) {
    return (unsigned)f2bf(a) | ((unsigned)f2bf(b) << 16);
}
__device__ __forceinline__ float bf_lo(unsigned v) {
    union { unsigned u; float f; } w; w.u = (v & 0xFFFFu) << 16; return w.f;
}
__device__ __forceinline__ float bf_hi(unsigned v) {
    union { unsigned u; float f; } w; w.u = v & 0xFFFF0000u; return w.f;
}
__device__ __forceinline__ void ld16(const void* g, void* l) {
    __builtin_amdgcn_global_load_lds(
        (const __attribute__((address_space(1))) unsigned int*)g,
        (__attribute__((address_space(3))) unsigned int*)l, 16, 0, 0);
}

// ---------------- CSR build ----------------
__global__ void k_count(const int* __restrict__ dst, int* __restrict__ deg, int E) {
    int e = blockIdx.x * blockDim.x + threadIdx.x;
    if (e < E) atomicAdd(&deg[dst[e]], 1);
}

__global__ void k_scan(const int* __restrict__ deg, int* __restrict__ row_ptr,
                       int* __restrict__ cursor, int n) {
    __shared__ int part[1024];
    int tid = threadIdx.x;
    int chunk = (n + 1023) / 1024;
    int start = tid * chunk;
    int end = min(start + chunk, n);
    int s = 0;
    for (int i = start; i < end; i++) s += deg[i];
    part[tid] = s;
    __syncthreads();
    for (int off = 1; off < 1024; off <<= 1) {
        int v = 0;
        if (tid >= off) v = part[tid - off];
        __syncthreads();
        part[tid] += v;
        __syncthreads();
    }
    int offset = (tid == 0) ? 0 : part[tid - 1];
    for (int i = start; i < end; i++) {
        row_ptr[i] = offset;
        cursor[i] = offset;
        offset += deg[i];
    }
    if (tid == 1023) row_ptr[n] = part[1023];
}

__global__ void k_fill(const int* __restrict__ src, const int* __restrict__ dst,
                       int* __restrict__ cursor, int* __restrict__ csr_src, int E) {
    int e = blockIdx.x * blockDim.x + threadIdx.x;
    if (e < E) {
        int d = dst[e];
        int pos = atomicAdd(&cursor[d], 1);
        csr_src[pos] = src[e];
    }
}

// ---------------- degree scalars ----------------
__global__ void k_delta(const int* __restrict__ deg, float* __restrict__ dsum, int n) {
    int i = blockIdx.x * blockDim.x + threadIdx.x;
    float v = (i < n) ? log1pf((float)deg[i]) : 0.f;
    #pragma unroll
    for (int off = 32; off > 0; off >>= 1) v += __shfl_down(v, off);
    if ((threadIdx.x & 63) == 0) atomicAdd(dsum, v);
}

__global__ void k_scalars(const int* __restrict__ deg, const float* __restrict__ dsum,
                          float* __restrict__ inv_d, float* __restrict__ amp,
                          float* __restrict__ att, int n) {
    int i = blockIdx.x * blockDim.x + threadIdx.x;
    if (i >= n) return;
    float delta = *dsum / (float)n;
    float d = fmaxf((float)deg[i], 1.f);
    float ld = log1pf(d);
    inv_d[i] = 1.f / d;
    amp[i] = ld / delta;
    att[i] = delta / ld;
}

// ---------------- node embedding (fp32 h + bf16 mirror) ----------------
__global__ void k_emb(const float* __restrict__ x, const float* __restrict__ W,
                      const float* __restrict__ b, float* __restrict__ h,
                      unsigned* __restrict__ hb2, int total2) {
    int i = blockIdx.x * blockDim.x + threadIdx.x;
    if (i >= total2) return;
    int node = i >> 6, c = (i & 63) * 2;
    float x0 = x[node * 3 + 0], x1 = x[node * 3 + 1], x2 = x[node * 3 + 2];
    float v0 = x0 * W[c] + x1 * W[DD + c] + x2 * W[2 * DD + c] + b[c];
    float v1 = x0 * W[c + 1] + x1 * W[DD + c + 1] + x2 * W[2 * DD + c + 1] + b[c + 1];
    ((float2*)h)[i] = make_float2(v0, v1);
    hb2[i] = pack_bf2(v0, v1);
}

// ---------------- weight convert: conv_W [L,1536,128] f32 -> Bt [L][3][128][512] bf16 ----
__global__ void k_wconv(const float* __restrict__ W, unsigned short* __restrict__ Bt, int total) {
    int o = blockIdx.x * blockDim.x + threadIdx.x;
    if (o >= total) return;
    int l = o / 196608;
    int r = o % 196608;
    int j = r >> 16;
    int r2 = r & 65535;
    int n = r2 >> 9;
    int k = r2 & 511;
    Bt[o] = f2bf(W[(size_t)l * 196608 + (size_t)(j * 512 + k) * 128 + n]);
}

// ---------------- PNA aggregation (bf16 gather, bf16 aggs out) ----------------
// one wave (64 threads) per node; lane t owns packed channels {2t, 2t+1}
__global__ void k_agg(const unsigned* __restrict__ hb2, const int* __restrict__ row_ptr,
                      const int* __restrict__ csr_src, const float* __restrict__ inv_d,
                      unsigned* __restrict__ aggs_u) {
    int node = blockIdx.x;
    int t = threadIdx.x;
    int beg = row_ptr[node], end = row_ptr[node + 1];
    float s1a = 0.f, s1b = 0.f, s2a = 0.f, s2b = 0.f;
    float mna = INFINITY, mnb = INFINITY, mxa = -INFINITY, mxb = -INFINITY;
    for (int e = beg; e < end; e++) {
        int s = csr_src[e];
        unsigned v = hb2[(size_t)s * 64 + t];
        float a = bf_lo(v), b = bf_hi(v);
        s1a += a; s2a += a * a; mna = fminf(mna, a); mxa = fmaxf(mxa, a);
        s1b += b; s2b += b * b; mnb = fminf(mnb, b); mxb = fmaxf(mxb, b);
    }
    float id = inv_d[node];
    float meana = s1a * id, meanb = s1b * id;
    float sda = sqrtf(fmaxf(s2a * id - meana * meana, 0.f) + EPSF);
    float sdb = sqrtf(fmaxf(s2b * id - meanb * meanb, 0.f) + EPSF);
    if (beg == end) { mna = 0.f; mxa = 0.f; mnb = 0.f; mxb = 0.f; }
    unsigned* outr = aggs_u + (size_t)node * 256;
    outr[t]       = pack_bf2(meana, meanb);
    outr[64 + t]  = pack_bf2(mna, mnb);
    outr[128 + t] = pack_bf2(mxa, mxb);
    outr[192 + t] = pack_bf2(sda, sdb);
}

// ---------------- MFMA GEMM ----------------
// A = aggs bf16 [N,512]; Bt = [3][128][512] bf16 (n-major, k contiguous).
// out[r,c] = sum_k A[r,k]*(B0 + amp[r]*B1 + att[r]*B2)[k,c] + bias[c]
// Block: 256 thr (4 waves), tile 64 rows x 128 cols; wave w owns cols [32w,32w+32).
__global__ __launch_bounds__(256) void k_gemm_mfma(
    const unsigned short* __restrict__ A, const unsigned short* __restrict__ Bt,
    const float* __restrict__ bias, const float* __restrict__ amp,
    const float* __restrict__ att, float* __restrict__ outp,
    float* __restrict__ bn_sum, float* __restrict__ bn_sq, int n) {
    __shared__ unsigned short As[64 * 32];
    __shared__ unsigned short Bs[3 * 128 * 32];
    int tid = threadIdx.x;
    int w = tid >> 6, lane = tid & 63;
    int quad = lane >> 4, l16 = lane & 15;
    int row0 = blockIdx.x * 64;

    f32x4 acc[4][2][3];
    #pragma unroll
    for (int rt = 0; rt < 4; rt++)
        #pragma unroll
        for (int ct = 0; ct < 2; ct++)
            #pragma unroll
            for (int j = 0; j < 3; j++) acc[rt][ct][j] = (f32x4)(0.f);

    // staging pointers
    const unsigned short* ga = A + (size_t)(row0 + (tid >> 2)) * 512 + (tid & 3) * 8;
    const unsigned short* gb[6];
    int ldsb[6];
    #pragma unroll
    for (int i = 0; i < 6; i++) {
        int c = i * 256 + tid;
        int j = c >> 9, rem = c & 511, nn = rem >> 2, kc = rem & 3;
        gb[i] = Bt + (size_t)(j * 128 + nn) * 512 + kc * 8;
        ldsb[i] = c * 8;
    }
    int a_off[4];
    #pragma unroll
    for (int rt = 0; rt < 4; rt++) a_off[rt] = (rt * 16 + l16) * 32 + quad * 8;
    int b_off[2][3];
    #pragma unroll
    for (int ct = 0; ct < 2; ct++)
        #pragma unroll
        for (int j = 0; j < 3; j++)
            b_off[ct][j] = j * 4096 + (w * 32 + ct * 16 + l16) * 32 + quad * 8;

    for (int k0 = 0; k0 < 512; k0 += 32) {
        __syncthreads();
        ld16(ga, &As[(size_t)tid * 8]); ga += 32;
        #pragma unroll
        for (int i = 0; i < 6; i++) { ld16(gb[i], &Bs[ldsb[i]]); gb[i] += 32; }
        __syncthreads();
        bf16x8 af[4];
        #pragma unroll
        for (int rt = 0; rt < 4; rt++) af[rt] = *(const bf16x8*)&As[a_off[rt]];
        #pragma unroll
        for (int ct = 0; ct < 2; ct++) {
            #pragma unroll
            for (int j = 0; j < 3; j++) {
                bf16x8 bf = *(const bf16x8*)&Bs[b_off[ct][j]];
                #pragma unroll
                for (int rt = 0; rt < 4; rt++)
                    acc[rt][ct][j] = __builtin_amdgcn_mfma_f32_16x16x32_bf16(
                        af[rt], bf, acc[rt][ct][j], 0, 0, 0);
            }
        }
    }

    // epilogue: combine j via amp/att, bias, write, BN partials
    float psum[2] = {0.f, 0.f}, psq[2] = {0.f, 0.f};
    #pragma unroll
    for (int rt = 0; rt < 4; rt++) {
        #pragma unroll
        for (int reg = 0; reg < 4; reg++) {
            int row = row0 + rt * 16 + quad * 4 + reg;
            if (row < n) {
                float am = amp[row], at = att[row];
                #pragma unroll
                for (int ct = 0; ct < 2; ct++) {
                    int col = w * 32 + ct * 16 + l16;
                    float v = acc[rt][ct][0][reg] + am * acc[rt][ct][1][reg]
                            + at * acc[rt][ct][2][reg] + bias[col];
                    outp[(size_t)row * DD + col] = v;
                    psum[ct] += v;
                    psq[ct] += v * v;
                }
            }
        }
    }
    #pragma unroll
    for (int ct = 0; ct < 2; ct++) {
        psum[ct] += __shfl_xor(psum[ct], 16, 64);
        psum[ct] += __shfl_xor(psum[ct], 32, 64);
        psq[ct]  += __shfl_xor(psq[ct], 16, 64);
        psq[ct]  += __shfl_xor(psq[ct], 32, 64);
    }
    if (quad == 0) {
        #pragma unroll
        for (int ct = 0; ct < 2; ct++) {
            int col = w * 32 + ct * 16 + l16;
            atomicAdd(&bn_sum[col], psum[ct]);
            atomicAdd(&bn_sq[col], psq[ct]);
        }
    }
}

// ---------------- BN stats ----------------
__global__ void k_bnstats(const float* __restrict__ bn_sum, const float* __restrict__ bn_sq,
                          const float* __restrict__ gamma, const float* __restrict__ beta,
                          float* __restrict__ scale, float* __restrict__ shift, int n) {
    int c = threadIdx.x;
    float mu = bn_sum[c] / (float)n;
    float var = bn_sq[c] / (float)n - mu * mu;
    float sc = rsqrtf(var + EPSF) * gamma[c];
    scale[c] = sc;
    shift[c] = beta[c] - mu * sc;
}

// ---------------- BN apply + relu + residual (updates h fp32 + bf16 mirror) --------
__global__ void k_bnapply(const float* __restrict__ outp, const float* __restrict__ scale,
                          const float* __restrict__ shift, float* __restrict__ h,
                          unsigned* __restrict__ hb2, int total2) {
    int i = blockIdx.x * blockDim.x + threadIdx.x;
    if (i >= total2) return;
    int c = (i & 63) * 2;
    float2 o = ((const float2*)outp)[i];
    float v0 = fmaxf(o.x * scale[c] + shift[c], 0.f);
    float v1 = fmaxf(o.y * scale[c + 1] + shift[c + 1], 0.f);
    float2 hh = ((float2*)h)[i];
    hh.x += v0; hh.y += v1;
    ((float2*)h)[i] = hh;
    hb2[i] = pack_bf2(hh.x, hh.y);
}

// ---------------- pool + MLP ----------------
__global__ void k_pool_mlp(const float* __restrict__ h, const int* __restrict__ batch,
                           const float* __restrict__ W1, const float* __restrict__ b1,
                           const float* __restrict__ W2, const float* __restrict__ b2,
                           const float* __restrict__ W3, const float* __restrict__ b3,
                           float* __restrict__ out, int n) {
    __shared__ float gvec[128];
    __shared__ float h1[64];
    __shared__ float h2[32];
    __shared__ int srange[2];
    int g = blockIdx.x;
    int t = threadIdx.x;
    if (t < 2) {
        int target = g + t;
        int lo = 0, hi = n;
        while (lo < hi) {
            int mid = (lo + hi) >> 1;
            if (batch[mid] < target) lo = mid + 1; else hi = mid;
        }
        srange[t] = lo;
    }
    __syncthreads();
    int s = srange[0], e = srange[1];
    float acc = 0.f;
    for (int i = s; i < e; i++) acc += h[(size_t)i * DD + t];
    float cnt = fmaxf((float)(e - s), 1.f);
    gvec[t] = acc / cnt;
    __syncthreads();
    if (t < 64) {
        float a = b1[t];
        for (int k = 0; k < 128; k++) a += gvec[k] * W1[k * 64 + t];
        h1[t] = fmaxf(a, 0.f);
    }
    __syncthreads();
    if (t < 32) {
        float a = b2[t];
        for (int k = 0; k < 64; k++) a += h1[k] * W2[k * 32 + t];
        h2[t] = fmaxf(a, 0.f);
    }
    __syncthreads();
    if (t < 10) {
        float a = b3[t];
        for (int k = 0; k < 32; k++) a += h2[k] * W3[k * 10 + t];
        out[g * NT + t] = a;
    }
}

extern "C" void kernel_launch(void* const* d_in, const int* in_sizes, int n_in,
                              void* d_out, int out_size, void* d_ws, size_t ws_size,
                              hipStream_t stream) {
    const float* x      = (const float*)d_in[0];
    const int*   eidx   = (const int*)d_in[1];
    const int*   batch  = (const int*)d_in[2];
    const float* emb_W  = (const float*)d_in[3];
    const float* emb_b  = (const float*)d_in[4];
    const float* conv_W = (const float*)d_in[5];
    const float* conv_b = (const float*)d_in[6];
    const float* bn_g   = (const float*)d_in[7];
    const float* bn_b   = (const float*)d_in[8];
    const float* W1 = (const float*)d_in[9];
    const float* b1 = (const float*)d_in[10];
    const float* W2 = (const float*)d_in[11];
    const float* b2 = (const float*)d_in[12];
    const float* W3 = (const float*)d_in[13];
    const float* b3 = (const float*)d_in[14];
    float* out = (float*)d_out;

    const int* src = eidx;
    const int* dst = eidx + NE;

    char* p = (char*)d_ws;
    auto carve = [&](size_t bytes) {
        void* r = (void*)p;
        p += (bytes + 255) & ~(size_t)255;
        return r;
    };
    int* deg      = (int*)carve(NN * 4);
    int* row_ptr  = (int*)carve((NN + 1) * 4);
    int* cursor   = (int*)carve(NN * 4);
    int* csr_src  = (int*)carve(NE * 4);
    float* inv_d  = (float*)carve(NN * 4);
    float* amp    = (float*)carve(NN * 4);
    float* att    = (float*)carve(NN * 4);
    float* dsum   = (float*)carve(4);
    float* bn_sum = (float*)carve(DD * 4);
    float* bn_sq  = (float*)carve(DD * 4);
    float* scale  = (float*)carve(DD * 4);
    float* shift  = (float*)carve(DD * 4);
    float* h      = (float*)carve((size_t)NN * DD * 4);
    unsigned* hb2 = (unsigned*)carve((size_t)NN * 64 * 4);
    unsigned* aggs_u = (unsigned*)carve((size_t)NN * 256 * 4);   // bf16 [N,512]
    float* outp   = (float*)carve((size_t)NN * DD * 4);          // must follow aggs (OOB pad)
    unsigned short* Bt = (unsigned short*)carve((size_t)NL * 3 * 128 * 512 * 2);

    hipMemsetAsync(deg, 0, NN * 4, stream);
    hipMemsetAsync(dsum, 0, 4, stream);

    k_count<<<(NE + 255) / 256, 256, 0, stream>>>(dst, deg, NE);
    k_scan<<<1, 1024, 0, stream>>>(deg, row_ptr, cursor, NN);
    k_fill<<<(NE + 255) / 256, 256, 0, stream>>>(src, dst, cursor, csr_src, NE);
    k_delta<<<(NN + 255) / 256, 256, 0, stream>>>(deg, dsum, NN);
    k_scalars<<<(NN + 255) / 256, 256, 0, stream>>>(deg, dsum, inv_d, amp, att, NN);
    k_emb<<<(NN * 64 + 255) / 256, 256, 0, stream>>>(x, emb_W, emb_b, h, hb2, NN * 64);
    k_wconv<<<(NL * 196608 + 255) / 256, 256, 0, stream>>>(conv_W, Bt, NL * 196608);

    int gemm_blocks = (NN + 63) / 64;
    for (int l = 0; l < NL; l++) {
        k_agg<<<NN, 64, 0, stream>>>(hb2, row_ptr, csr_src, inv_d, aggs_u);
        hipMemsetAsync(bn_sum, 0, DD * 4, stream);
        hipMemsetAsync(bn_sq, 0, DD * 4, stream);
        k_gemm_mfma<<<gemm_blocks, 256, 0, stream>>>(
            (const unsigned short*)aggs_u, Bt + (size_t)l * 3 * 128 * 512,
            conv_b + l * DD, amp, att, outp, bn_sum, bn_sq, NN);
        k_bnstats<<<1, DD, 0, stream>>>(bn_sum, bn_sq, bn_g + l * DD, bn_b + l * DD,
                                        scale, shift, NN);
        k_bnapply<<<(NN * 64 + 255) / 256, 256, 0, stream>>>(outp, scale, shift, h, hb2, NN * 64);
    }

    k_pool_mlp<<<NG, 128, 0, stream>>>(h, batch, W1, b1, W2, b2, W3, b3, out, NN);
}